// Round 19
// baseline (324.307 us; speedup 1.0000x reference)
//
#include <hip/hip_runtime.h>
#include <hip/hip_fp16.h>

#define N_NODES 100000
#define N_EDGES 3200000
#define DIM 128
#define NG 64
#define GS_CHUNKS 16

#define KSH 8
#define BKT 256
#define NBKT ((N_NODES + BKT - 1) / BKT)      // 391
#define CHUNK 4096
#define NBLK ((N_EDGES + CHUNK - 1) / CHUNK)  // 782

using f16x8 = __attribute__((ext_vector_type(8))) _Float16;
using f32x4 = __attribute__((ext_vector_type(4))) float;

// ---------------- coarse histograms (8-way privatized, 512 thr) + per-row totals ----------------
__global__ __launch_bounds__(512) void k_hist1(const int* __restrict__ src, const int* __restrict__ dst,
                                               int* __restrict__ histD, int* __restrict__ histS,
                                               int* __restrict__ rowtot) {
    __shared__ int hD[8 * NBKT];
    __shared__ int hS[8 * NBKT];
    int t = threadIdx.x, blk = blockIdx.x;
    int w = t >> 6;   // wave 0..7
    for (int i = t; i < 8 * NBKT; i += 512) { hD[i] = 0; hS[i] = 0; }
    __syncthreads();
    int base = blk * CHUNK;
    for (int i = t; i < CHUNK; i += 512) {
        int e = base + i;
        if (e < N_EDGES) {
            atomicAdd(&hD[w * NBKT + (dst[e] >> KSH)], 1);
            atomicAdd(&hS[w * NBKT + (src[e] >> KSH)], 1);
        }
    }
    __syncthreads();
    for (int i = t; i < NBKT; i += 512) {
        int d = 0, s = 0;
        #pragma unroll
        for (int k = 0; k < 8; k++) { d += hD[k * NBKT + i]; s += hS[k * NBKT + i]; }
        histD[i * NBLK + blk] = d;
        histS[i * NBLK + blk] = s;
        atomicAdd(&rowtot[i], d);
        atomicAdd(&rowtot[NBKT + i], s);
    }
}

// ---------------- per-row exclusive scan + base (2 elements per thread, NBLK=782) ----------------
__global__ __launch_bounds__(512) void k_rowapply(int* __restrict__ histD, int* __restrict__ histS,
                                                  const int* __restrict__ rowtot) {
    __shared__ int sh[512];
    __shared__ int red[512];
    int r = blockIdx.x;
    int half = (r < NBKT) ? 0 : 1;
    int pos = half ? (r - NBKT) : r;
    int* a = half ? (histS + (size_t)pos * NBLK) : (histD + (size_t)pos * NBLK);
    int t = threadIdx.x;
    red[t] = (t < pos) ? rowtot[half * NBKT + t] : 0;
    __syncthreads();
    for (int off = 256; off > 0; off >>= 1) {
        if (t < off) red[t] += red[t + off];
        __syncthreads();
    }
    int basev = red[0];
    int i0 = 2 * t, i1 = 2 * t + 1;
    int v0 = (i0 < NBLK) ? a[i0] : 0;
    int v1 = (i1 < NBLK) ? a[i1] : 0;
    int x = v0 + v1;
    sh[t] = x; __syncthreads();
    for (int off = 1; off < 512; off <<= 1) {
        int y = sh[t]; int u = (t >= off) ? sh[t - off] : 0;
        __syncthreads(); sh[t] = y + u; __syncthreads();
    }
    int excl = sh[t] - x + basev;
    if (i0 < NBLK) a[i0] = excl;
    if (i1 < NBLK) a[i1] = excl + v0;
}

// ---------------- scatter edges (512 thr): LDS bucket-sorted stage, run-coalesced flush ----------------
__global__ __launch_bounds__(512) void k_scatter1(const int* __restrict__ src, const int* __restrict__ dst,
                                                  const int* __restrict__ histD, const int* __restrict__ histS,
                                                  int* __restrict__ bufD, unsigned short* __restrict__ bufS) {
    __shared__ int gbD[NBKT], cntD[NBKT], offD[NBKT], curD[NBKT];
    __shared__ int gbS[NBKT], cntS[NBKT], offS[NBKT], curS[NBKT];
    __shared__ int stageD[CHUNK];
    __shared__ unsigned short stageS[CHUNK];
    int t = threadIdx.x, blk = blockIdx.x;
    for (int b = t; b < NBKT; b += 512) {
        int idx = b * NBLK + blk;
        int st = histD[idx];
        int nx = (idx + 1 < NBKT * NBLK) ? histD[idx + 1] : N_EDGES;
        gbD[b] = st; cntD[b] = nx - st;
        int st2 = histS[idx];
        int nx2 = (idx + 1 < NBKT * NBLK) ? histS[idx + 1] : N_EDGES;
        gbS[b] = st2; cntS[b] = nx2 - st2;
    }
    __syncthreads();
    if (t < 64) {
        int lane = t;
        int base7 = lane * 7;
        int loc[7]; int s7 = 0;
        #pragma unroll
        for (int k = 0; k < 7; k++) { int b = base7 + k; loc[k] = s7; s7 += (b < NBKT) ? cntD[b] : 0; }
        int x = s7;
        #pragma unroll
        for (int off = 1; off < 64; off <<= 1) { int y = __shfl_up(x, off); if (lane >= off) x += y; }
        int excl = x - s7;
        #pragma unroll
        for (int k = 0; k < 7; k++) { int b = base7 + k; if (b < NBKT) { offD[b] = excl + loc[k]; curD[b] = excl + loc[k]; } }
    } else if (t < 128) {
        int lane = t - 64;
        int base7 = lane * 7;
        int loc[7]; int s7 = 0;
        #pragma unroll
        for (int k = 0; k < 7; k++) { int b = base7 + k; loc[k] = s7; s7 += (b < NBKT) ? cntS[b] : 0; }
        int x = s7;
        #pragma unroll
        for (int off = 1; off < 64; off <<= 1) { int y = __shfl_up(x, off); if (lane >= off) x += y; }
        int excl = x - s7;
        #pragma unroll
        for (int k = 0; k < 7; k++) { int b = base7 + k; if (b < NBKT) { offS[b] = excl + loc[k]; curS[b] = excl + loc[k]; } }
    }
    __syncthreads();
    int base = blk * CHUNK;
    for (int i = t; i < CHUNK; i += 512) {
        int e = base + i;
        if (e < N_EDGES) {
            int s = src[e], d = dst[e];
            int pD = atomicAdd(&curD[d >> KSH], 1);
            stageD[pD] = ((d & (BKT - 1)) << 17) | s;
            int pS = atomicAdd(&curS[s >> KSH], 1);
            stageS[pS] = (unsigned short)(s & (BKT - 1));
        }
    }
    __syncthreads();
    int wv = t >> 6, lane = t & 63;
    for (int b = wv; b < NBKT; b += 8) {
        int c = cntD[b], o = offD[b], g = gbD[b];
        for (int i = lane; i < c; i += 64) bufD[g + i] = stageD[o + i];
        int c2 = cntS[b], o2 = offS[b], g2 = gbS[b];
        for (int i = lane; i < c2; i += 64) bufS[g2 + i] = stageS[o2 + i];
    }
}

// ---------------- fused pass2 (512 thr, privatized count bins) ----------------
__global__ __launch_bounds__(512) void k_pass2both(const int* __restrict__ bufD,
                                               const unsigned short* __restrict__ bufS,
                                               const int* __restrict__ histD,
                                               const int* __restrict__ histS,
                                               const float* __restrict__ feat,
                                               int* __restrict__ rowptr, float* __restrict__ norm_dst,
                                               float* __restrict__ norm_src,
                                               int* __restrict__ col, unsigned* __restrict__ feat8) {
    __shared__ int priv[8 * BKT];
    __shared__ int binc[BKT];
    __shared__ int binoff[BKT];
    __shared__ float snorm[BKT];
    int bb = blockIdx.x, t = threadIdx.x;
    int w = t >> 6;
    if (bb < NBKT) {
        int b = bb;
        int start = histD[b * NBLK];
        int end = (b + 1 < NBKT) ? histD[(b + 1) * NBLK] : N_EDGES;
        for (int i = t; i < 8 * BKT; i += 512) priv[i] = 0;
        __syncthreads();
        for (int i = start + t; i < end; i += 512) atomicAdd(&priv[w * BKT + (bufD[i] >> 17)], 1);
        __syncthreads();
        if (t < BKT) {
            int s = 0;
            #pragma unroll
            for (int k = 0; k < 8; k++) s += priv[k * BKT + t];
            binc[t] = s;
        }
        __syncthreads();
        if (t < 64) {
            int base4 = t * 4;
            int loc[4]; int s4 = 0;
            #pragma unroll
            for (int k = 0; k < 4; k++) { loc[k] = s4; s4 += binc[base4 + k]; }
            int x = s4;
            #pragma unroll
            for (int off = 1; off < 64; off <<= 1) {
                int y = __shfl_up(x, off);
                if (t >= off) x += y;
            }
            int excl = x - s4;
            #pragma unroll
            for (int k = 0; k < 4; k++) binoff[base4 + k] = excl + loc[k];
        }
        __syncthreads();
        int nb = N_NODES - b * BKT; if (nb > BKT) nb = BKT;
        if (t < nb) {
            rowptr[b * BKT + t] = start + binoff[t];
            int c = binc[t]; if (c < 1) c = 1;
            norm_dst[b * BKT + t] = rsqrtf((float)c);
        }
        if (b == NBKT - 1 && t == 0) rowptr[N_NODES] = N_EDGES;
        __syncthreads();
        if (t < BKT) binc[t] = binoff[t];
        __syncthreads();
        for (int i = start + t; i < end; i += 512) {
            int v = bufD[i];
            int ld = v >> 17, s = v & 0x1FFFF;
            int p = atomicAdd(&binc[ld], 1);
            col[start + p] = s;
        }
    } else {
        int b = bb - NBKT;
        int start = histS[b * NBLK];
        int end = (b + 1 < NBKT) ? histS[(b + 1) * NBLK] : N_EDGES;
        for (int i = t; i < 8 * BKT; i += 512) priv[i] = 0;
        __syncthreads();
        for (int i = start + t; i < end; i += 512) atomicAdd(&priv[w * BKT + bufS[i]], 1);
        __syncthreads();
        int nb = N_NODES - b * BKT; if (nb > BKT) nb = BKT;
        if (t < nb) {
            int c = 0;
            #pragma unroll
            for (int k = 0; k < 8; k++) c += priv[k * BKT + t];
            if (c < 1) c = 1;
            float sc = rsqrtf((float)c);
            norm_src[b * BKT + t] = sc;
            snorm[t] = sc;
        }
        __syncthreads();
        const float4* fin = (const float4*)feat;
        int nq = nb * 32;
        for (int i = t; i < nq; i += 512) {
            int nl = i >> 5, q = i & 31;
            float sc = snorm[nl];
            float4 v = fin[((size_t)(b * BKT + nl)) * 32 + q];
            unsigned wv = 0;
            wv = __builtin_amdgcn_cvt_pk_fp8_f32(v.x * sc, v.y * sc, wv, 0);
            wv = __builtin_amdgcn_cvt_pk_fp8_f32(v.z * sc, v.w * sc, wv, 1);
            feat8[((size_t)(b * BKT + nl)) * 32 + q] = wv;
        }
    }
}

// ---------------- SpMM (fp8 gather, 8 nodes per wave, 8 edges in flight) ----------------
#define ACC8(r) do {                                                                  \
    auto p0 = __builtin_amdgcn_cvt_pk_f32_fp8((r).x, 0); a0 += p0[0]; a1 += p0[1];    \
    auto p1 = __builtin_amdgcn_cvt_pk_f32_fp8((r).x, 1); a2 += p1[0]; a3 += p1[1];    \
    auto p2 = __builtin_amdgcn_cvt_pk_f32_fp8((r).y, 0); a4 += p2[0]; a5 += p2[1];    \
    auto p3 = __builtin_amdgcn_cvt_pk_f32_fp8((r).y, 1); a6 += p3[0]; a7 += p3[1];    \
    auto p4 = __builtin_amdgcn_cvt_pk_f32_fp8((r).z, 0); a8 += p4[0]; a9 += p4[1];    \
    auto p5 = __builtin_amdgcn_cvt_pk_f32_fp8((r).z, 1); a10 += p5[0]; a11 += p5[1];  \
    auto p6 = __builtin_amdgcn_cvt_pk_f32_fp8((r).w, 0); a12 += p6[0]; a13 += p6[1];  \
    auto p7 = __builtin_amdgcn_cvt_pk_f32_fp8((r).w, 1); a14 += p7[0]; a15 += p7[1];  \
} while (0)

__global__ __launch_bounds__(256) void k_spmm8(const unsigned char* __restrict__ in,
                       const int* __restrict__ rowptr, const int* __restrict__ col,
                       const float* __restrict__ norm_dst, __half2* __restrict__ out) {
    int wid = (blockIdx.x * 256 + threadIdx.x) >> 6;
    int lane = threadIdx.x & 63;
    int rg = lane >> 3, l8 = lane & 7;
    int node = wid * 8 + rg;
    if (node >= N_NODES) return;
    int jb = rowptr[node], je = rowptr[node + 1];
    float a0 = 0.f, a1 = 0.f, a2 = 0.f, a3 = 0.f, a4 = 0.f, a5 = 0.f, a6 = 0.f, a7 = 0.f;
    float a8 = 0.f, a9 = 0.f, a10 = 0.f, a11 = 0.f, a12 = 0.f, a13 = 0.f, a14 = 0.f, a15 = 0.f;
    int j = jb;
    for (; j + 8 <= je; j += 8) {
        int s0 = col[j], s1 = col[j + 1], s2 = col[j + 2], s3 = col[j + 3];
        int s4 = col[j + 4], s5 = col[j + 5], s6 = col[j + 6], s7 = col[j + 7];
        uint4 r0 = *(const uint4*)&in[(size_t)s0 * 128 + l8 * 16];
        uint4 r1 = *(const uint4*)&in[(size_t)s1 * 128 + l8 * 16];
        uint4 r2 = *(const uint4*)&in[(size_t)s2 * 128 + l8 * 16];
        uint4 r3 = *(const uint4*)&in[(size_t)s3 * 128 + l8 * 16];
        uint4 r4 = *(const uint4*)&in[(size_t)s4 * 128 + l8 * 16];
        uint4 r5 = *(const uint4*)&in[(size_t)s5 * 128 + l8 * 16];
        uint4 r6 = *(const uint4*)&in[(size_t)s6 * 128 + l8 * 16];
        uint4 r7 = *(const uint4*)&in[(size_t)s7 * 128 + l8 * 16];
        ACC8(r0); ACC8(r1); ACC8(r2); ACC8(r3);
        ACC8(r4); ACC8(r5); ACC8(r6); ACC8(r7);
    }
    if (j + 4 <= je) {
        int s0 = col[j], s1 = col[j + 1], s2 = col[j + 2], s3 = col[j + 3];
        uint4 r0 = *(const uint4*)&in[(size_t)s0 * 128 + l8 * 16];
        uint4 r1 = *(const uint4*)&in[(size_t)s1 * 128 + l8 * 16];
        uint4 r2 = *(const uint4*)&in[(size_t)s2 * 128 + l8 * 16];
        uint4 r3 = *(const uint4*)&in[(size_t)s3 * 128 + l8 * 16];
        ACC8(r0); ACC8(r1); ACC8(r2); ACC8(r3);
        j += 4;
    }
    if (j + 2 <= je) {
        int s0 = col[j], s1 = col[j + 1];
        uint4 r0 = *(const uint4*)&in[(size_t)s0 * 128 + l8 * 16];
        uint4 r1 = *(const uint4*)&in[(size_t)s1 * 128 + l8 * 16];
        ACC8(r0); ACC8(r1);
        j += 2;
    }
    if (j < je) {
        int s0 = col[j];
        uint4 r0 = *(const uint4*)&in[(size_t)s0 * 128 + l8 * 16];
        ACC8(r0);
    }
    float nd = norm_dst[node];
    __half2 h0 = __floats2half2_rn(a0 * nd, a1 * nd);
    __half2 h1 = __floats2half2_rn(a2 * nd, a3 * nd);
    __half2 h2 = __floats2half2_rn(a4 * nd, a5 * nd);
    __half2 h3 = __floats2half2_rn(a6 * nd, a7 * nd);
    __half2 h4 = __floats2half2_rn(a8 * nd, a9 * nd);
    __half2 h5 = __floats2half2_rn(a10 * nd, a11 * nd);
    __half2 h6 = __floats2half2_rn(a12 * nd, a13 * nd);
    __half2 h7 = __floats2half2_rn(a14 * nd, a15 * nd);
    uint4 o0, o1;
    o0.x = *(unsigned*)&h0; o0.y = *(unsigned*)&h1;
    o0.z = *(unsigned*)&h2; o0.w = *(unsigned*)&h3;
    o1.x = *(unsigned*)&h4; o1.y = *(unsigned*)&h5;
    o1.z = *(unsigned*)&h6; o1.w = *(unsigned*)&h7;
    *(uint4*)&out[(size_t)node * 64 + l8 * 8] = o0;
    *(uint4*)&out[(size_t)node * 64 + l8 * 8 + 4] = o1;
}

// ---------------- MFMA GEMM: [N,128]f16 @ [128,128] + bias, relu, (opt rowscale) ----------------
template <bool SCALE, bool OUT8>
__global__ __launch_bounds__(256) void k_gemm_mfma(const __half* __restrict__ A,
        const float* __restrict__ W, const float* __restrict__ bias,
        const float* __restrict__ rowscale, void* __restrict__ outp) {
    __shared__ _Float16 lds[128 * 136];
    int tid = threadIdx.x;
    for (int idx = tid * 4; idx < DIM * DIM; idx += 256 * 4) {
        int k = idx >> 7, n = idx & 127;
        float4 w = *(const float4*)&W[idx];
        lds[(n + 0) * 136 + k] = (_Float16)w.x;
        lds[(n + 1) * 136 + k] = (_Float16)w.y;
        lds[(n + 2) * 136 + k] = (_Float16)w.z;
        lds[(n + 3) * 136 + k] = (_Float16)w.w;
    }
    __syncthreads();
    int wv = tid >> 6, lane = tid & 63;
    int rbase = blockIdx.x * 64 + wv * 16;
    int l15 = lane & 15, kg = lane >> 4;
    int arow = rbase + l15; if (arow >= N_NODES) arow = N_NODES - 1;
    const _Float16* Af = (const _Float16*)A + (size_t)arow * DIM + kg * 8;
    f16x8 a0 = *(const f16x8*)(Af + 0);
    f16x8 a1 = *(const f16x8*)(Af + 32);
    f16x8 a2 = *(const f16x8*)(Af + 64);
    f16x8 a3 = *(const f16x8*)(Af + 96);
    f32x4 acc[8];
    #pragma unroll
    for (int nt = 0; nt < 8; nt++) acc[nt] = (f32x4){0.f, 0.f, 0.f, 0.f};
    #pragma unroll
    for (int nt = 0; nt < 8; nt++) {
        const _Float16* bb = &lds[(nt * 16 + l15) * 136 + kg * 8];
        f16x8 b0 = *(const f16x8*)(bb + 0);
        f16x8 b1 = *(const f16x8*)(bb + 32);
        f16x8 b2 = *(const f16x8*)(bb + 64);
        f16x8 b3 = *(const f16x8*)(bb + 96);
        acc[nt] = __builtin_amdgcn_mfma_f32_16x16x32_f16(a0, b0, acc[nt], 0, 0, 0);
        acc[nt] = __builtin_amdgcn_mfma_f32_16x16x32_f16(a1, b1, acc[nt], 0, 0, 0);
        acc[nt] = __builtin_amdgcn_mfma_f32_16x16x32_f16(a2, b2, acc[nt], 0, 0, 0);
        acc[nt] = __builtin_amdgcn_mfma_f32_16x16x32_f16(a3, b3, acc[nt], 0, 0, 0);
    }
    __syncthreads();
    float bsc[4];
    #pragma unroll
    for (int r = 0; r < 4; r++) {
        if (SCALE) {
            int row = rbase + kg * 4 + r; if (row >= N_NODES) row = N_NODES - 1;
            bsc[r] = rowscale[row];
        } else bsc[r] = 1.f;
    }
    #pragma unroll
    for (int nt = 0; nt < 8; nt++) {
        float bv = bias[nt * 16 + l15];
        #pragma unroll
        for (int r = 0; r < 4; r++) {
            float v = fmaxf(acc[nt][r] + bv, 0.f) * bsc[r];
            lds[(size_t)(wv * 16 + kg * 4 + r) * 136 + nt * 16 + l15] = (_Float16)v;
        }
    }
    __syncthreads();
    #pragma unroll
    for (int t = 0; t < 4; t++) {
        int lrow = wv * 16 + t * 4 + kg;
        int grow = rbase + t * 4 + kg;
        f16x8 v = *(const f16x8*)&lds[(size_t)lrow * 136 + l15 * 8];
        if (grow < N_NODES) {
            if (OUT8) {
                unsigned w0 = 0, w1 = 0;
                w0 = __builtin_amdgcn_cvt_pk_fp8_f32((float)v[0], (float)v[1], w0, 0);
                w0 = __builtin_amdgcn_cvt_pk_fp8_f32((float)v[2], (float)v[3], w0, 1);
                w1 = __builtin_amdgcn_cvt_pk_fp8_f32((float)v[4], (float)v[5], w1, 0);
                w1 = __builtin_amdgcn_cvt_pk_fp8_f32((float)v[6], (float)v[7], w1, 1);
                uint2 o; o.x = w0; o.y = w1;
                *(uint2*)&((unsigned char*)outp)[(size_t)grow * 128 + l15 * 8] = o;
            } else {
                *(f16x8*)&((_Float16*)outp)[(size_t)grow * DIM + l15 * 8] = v;
            }
        }
    }
}

// ---------------- per-graph partial feature sums (bounds computed inline) ----------------
__global__ __launch_bounds__(256) void k_graphsum_part(const __half2* __restrict__ h,
                           const int* __restrict__ gids, float* __restrict__ partial) {
    __shared__ float redx[256];
    __shared__ float redy[256];
    __shared__ int sb[2];
    int g = blockIdx.x;
    int c = blockIdx.y;
    if (threadIdx.x == 0) {
        int lo = 0, hi = N_NODES;
        while (lo < hi) { int mid = (lo + hi) >> 1; if (gids[mid] < g) lo = mid + 1; else hi = mid; }
        sb[0] = lo;
        lo = 0; hi = N_NODES;
        while (lo < hi) { int mid = (lo + hi) >> 1; if (gids[mid] <= g) lo = mid + 1; else hi = mid; }
        sb[1] = lo;
    }
    __syncthreads();
    int s = sb[0], e = sb[1];
    int p = threadIdx.x & 63;
    int r = threadIdx.x >> 6;
    int clen = (e - s + GS_CHUNKS - 1) / GS_CHUNKS;
    int b0 = s + c * clen;
    int b1 = b0 + clen; if (b1 > e) b1 = e;
    float ax = 0.f, ay = 0.f;
    for (int nd = b0 + r; nd < b1; nd += 4) {
        float2 f = __half22float2(h[(size_t)nd * 64 + p]);
        ax += f.x; ay += f.y;
    }
    redx[threadIdx.x] = ax; redy[threadIdx.x] = ay;
    __syncthreads();
    if (threadIdx.x < 64) {
        float sx = redx[threadIdx.x] + redx[threadIdx.x + 64] + redx[threadIdx.x + 128] + redx[threadIdx.x + 192];
        float sy = redy[threadIdx.x] + redy[threadIdx.x + 64] + redy[threadIdx.x + 128] + redy[threadIdx.x + 192];
        float* pp = &partial[((size_t)g * GS_CHUNKS + c) * DIM];
        pp[2 * threadIdx.x] = sx;
        pp[2 * threadIdx.x + 1] = sy;
    }
}

// ---------------- fused combine + MLP readout ----------------
__global__ __launch_bounds__(128) void k_mlp(const float* __restrict__ partial,
                      const int* __restrict__ gids,
                      const float* __restrict__ Wm0, const float* __restrict__ bm0,
                      const float* __restrict__ Wm1, const float* __restrict__ bm1,
                      const float* __restrict__ Wm2, const float* __restrict__ bm2,
                      const float* __restrict__ Wm3, const float* __restrict__ bm3,
                      float* __restrict__ out) {
    __shared__ float hb[DIM];
    __shared__ float l0[64];
    __shared__ float l1[32];
    __shared__ float l2[16];
    __shared__ int scnt;
    int g = blockIdx.x;
    int t = threadIdx.x;
    if (t == 0) {
        int lo = 0, hi = N_NODES;
        while (lo < hi) { int mid = (lo + hi) >> 1; if (gids[mid] < g) lo = mid + 1; else hi = mid; }
        int s = lo;
        lo = 0; hi = N_NODES;
        while (lo < hi) { int mid = (lo + hi) >> 1; if (gids[mid] <= g) lo = mid + 1; else hi = mid; }
        int c = lo - s; if (c < 1) c = 1;
        scnt = c;
    }
    __syncthreads();
    float acc = 0.f;
    #pragma unroll
    for (int c = 0; c < GS_CHUNKS; c++)
        acc += partial[((size_t)g * GS_CHUNKS + c) * DIM + t];
    hb[t] = acc / (float)scnt;
    __syncthreads();
    if (t < 64) {
        float a = bm0[t];
        for (int k = 0; k < 128; k++) a += hb[k] * Wm0[k * 64 + t];
        l0[t] = fmaxf(a, 0.f);
    }
    __syncthreads();
    if (t < 32) {
        float a = bm1[t];
        for (int k = 0; k < 64; k++) a += l0[k] * Wm1[k * 32 + t];
        l1[t] = fmaxf(a, 0.f);
    }
    __syncthreads();
    if (t < 16) {
        float a = bm2[t];
        for (int k = 0; k < 32; k++) a += l1[k] * Wm2[k * 16 + t];
        l2[t] = fmaxf(a, 0.f);
    }
    __syncthreads();
    if (t == 0) {
        float a = bm3[0];
        for (int k = 0; k < 16; k++) a += l2[k] * Wm3[k];
        out[g] = a;
    }
}

extern "C" void kernel_launch(void* const* d_in, const int* in_sizes, int n_in,
                              void* d_out, int out_size, void* d_ws, size_t ws_size,
                              hipStream_t stream) {
    const float* feat = (const float*)d_in[0];
    const int*   src  = (const int*)d_in[1];
    const int*   dst  = (const int*)d_in[2];
    const int*   gids = (const int*)d_in[3];
    const float* W1   = (const float*)d_in[5];
    const float* b1   = (const float*)d_in[6];
    const float* W2   = (const float*)d_in[7];
    const float* b2   = (const float*)d_in[8];
    const float* Wm0  = (const float*)d_in[9];
    const float* bm0  = (const float*)d_in[10];
    const float* Wm1  = (const float*)d_in[11];
    const float* bm1  = (const float*)d_in[12];
    const float* Wm2  = (const float*)d_in[13];
    const float* bm2  = (const float*)d_in[14];
    const float* Wm3  = (const float*)d_in[15];
    const float* bm3  = (const float*)d_in[16];
    float* out = (float*)d_out;

    char* ws = (char*)d_ws;
    size_t off = 0;
    auto alloc = [&](size_t bytes) -> void* {
        void* p = ws + off;
        off += (bytes + 511) & ~(size_t)511;
        return p;
    };
    float* norm_src = (float*)alloc((size_t)N_NODES * 4);
    float* norm_dst = (float*)alloc((size_t)N_NODES * 4);
    int* rowptr   = (int*)alloc((size_t)(N_NODES + 1) * 4);
    int* histD    = (int*)alloc((size_t)NBKT * NBLK * 4);
    int* histS    = (int*)alloc((size_t)NBKT * NBLK * 4);
    int* rowtot   = (int*)alloc((size_t)(2 * NBKT) * 4);
    int* bufD     = (int*)alloc((size_t)N_EDGES * 4);
    unsigned short* bufS = (unsigned short*)alloc((size_t)N_EDGES * 2);
    int* col      = (int*)alloc((size_t)N_EDGES * 4);
    unsigned char* feat8 = (unsigned char*)alloc((size_t)N_NODES * DIM);
    unsigned char* h8    = (unsigned char*)alloc((size_t)N_NODES * DIM);
    __half* s16   = (__half*)alloc((size_t)N_NODES * DIM * 2);
    __half* g16   = (__half*)alloc((size_t)N_NODES * DIM * 2);
    float* partial = (float*)alloc((size_t)NG * GS_CHUNKS * DIM * 4);

    hipMemsetAsync(rowtot, 0, (size_t)(2 * NBKT) * 4, stream);

    k_hist1<<<NBLK, 512, 0, stream>>>(src, dst, histD, histS, rowtot);
    k_rowapply<<<2 * NBKT, 512, 0, stream>>>(histD, histS, rowtot);
    k_scatter1<<<NBLK, 512, 0, stream>>>(src, dst, histD, histS, bufD, bufS);
    k_pass2both<<<2 * NBKT, 512, 0, stream>>>(bufD, bufS, histD, histS, feat,
                                              rowptr, norm_dst, norm_src, col, (unsigned*)feat8);

    int sb2 = (N_NODES + 31) / 32;   // 8 nodes per wave, 4 waves per block
    int gb = (N_NODES + 63) / 64;
    k_spmm8<<<sb2, 256, 0, stream>>>(feat8, rowptr, col, norm_dst, (__half2*)s16);
    k_gemm_mfma<true, true><<<gb, 256, 0, stream>>>(s16, W1, b1, norm_src, h8);
    k_spmm8<<<sb2, 256, 0, stream>>>(h8, rowptr, col, norm_dst, (__half2*)s16);
    k_gemm_mfma<false, false><<<gb, 256, 0, stream>>>(s16, W2, b2, nullptr, g16);

    dim3 gsg(NG, GS_CHUNKS);
    k_graphsum_part<<<gsg, 256, 0, stream>>>((const __half2*)g16, gids, partial);
    k_mlp<<<NG, 128, 0, stream>>>(partial, gids, Wm0, bm0, Wm1, bm1, Wm2, bm2, Wm3, bm3, out);
}

// Round 20
// 302.984 us; speedup vs baseline: 1.0704x; 1.0704x over previous
//
#include <hip/hip_runtime.h>
#include <hip/hip_fp16.h>

#define N_NODES 100000
#define N_EDGES 3200000
#define DIM 128
#define NG 64
#define GS_CHUNKS 16

#define KSH 8
#define BKT 256
#define NBKT ((N_NODES + BKT - 1) / BKT)      // 391
#define CHUNK 8192
#define NBLK ((N_EDGES + CHUNK - 1) / CHUNK)  // 391

using f16x8 = __attribute__((ext_vector_type(8))) _Float16;
using f32x4 = __attribute__((ext_vector_type(4))) float;

// ---------------- coarse histograms (8-way privatized, 512 thr) + per-row totals ----------------
__global__ __launch_bounds__(512) void k_hist1(const int* __restrict__ src, const int* __restrict__ dst,
                                               int* __restrict__ histD, int* __restrict__ histS,
                                               int* __restrict__ rowtot) {
    __shared__ int hD[8 * NBKT];
    __shared__ int hS[8 * NBKT];
    int t = threadIdx.x, blk = blockIdx.x;
    int w = t >> 6;   // wave 0..7
    for (int i = t; i < 8 * NBKT; i += 512) { hD[i] = 0; hS[i] = 0; }
    __syncthreads();
    int base = blk * CHUNK;
    for (int i = t; i < CHUNK; i += 512) {
        int e = base + i;
        if (e < N_EDGES) {
            atomicAdd(&hD[w * NBKT + (dst[e] >> KSH)], 1);
            atomicAdd(&hS[w * NBKT + (src[e] >> KSH)], 1);
        }
    }
    __syncthreads();
    for (int i = t; i < NBKT; i += 512) {
        int d = 0, s = 0;
        #pragma unroll
        for (int k = 0; k < 8; k++) { d += hD[k * NBKT + i]; s += hS[k * NBKT + i]; }
        histD[i * NBLK + blk] = d;
        histS[i * NBLK + blk] = s;
        atomicAdd(&rowtot[i], d);
        atomicAdd(&rowtot[NBKT + i], s);
    }
}

// ---------------- per-row exclusive scan + base ----------------
__global__ __launch_bounds__(512) void k_rowapply(int* __restrict__ histD, int* __restrict__ histS,
                                                  const int* __restrict__ rowtot) {
    __shared__ int sh[512];
    __shared__ int red[512];
    int r = blockIdx.x;
    int half = (r < NBKT) ? 0 : 1;
    int pos = half ? (r - NBKT) : r;
    int* a = half ? (histS + (size_t)pos * NBLK) : (histD + (size_t)pos * NBLK);
    int t = threadIdx.x;
    red[t] = (t < pos) ? rowtot[half * NBKT + t] : 0;
    __syncthreads();
    for (int off = 256; off > 0; off >>= 1) {
        if (t < off) red[t] += red[t + off];
        __syncthreads();
    }
    int basev = red[0];
    int x = (t < NBLK) ? a[t] : 0;
    sh[t] = x; __syncthreads();
    for (int off = 1; off < 512; off <<= 1) {
        int y = sh[t]; int u = (t >= off) ? sh[t - off] : 0;
        __syncthreads(); sh[t] = y + u; __syncthreads();
    }
    if (t < NBLK) a[t] = sh[t] - x + basev;
}

// ---------------- scatter edges (512 thr): LDS bucket-sorted stage, run-coalesced flush ----------------
__global__ __launch_bounds__(512) void k_scatter1(const int* __restrict__ src, const int* __restrict__ dst,
                                                  const int* __restrict__ histD, const int* __restrict__ histS,
                                                  int* __restrict__ bufD, unsigned short* __restrict__ bufS) {
    __shared__ int gbD[NBKT], cntD[NBKT], offD[NBKT], curD[NBKT];
    __shared__ int gbS[NBKT], cntS[NBKT], offS[NBKT], curS[NBKT];
    __shared__ int stageD[CHUNK];
    __shared__ unsigned short stageS[CHUNK];
    int t = threadIdx.x, blk = blockIdx.x;
    for (int b = t; b < NBKT; b += 512) {
        int idx = b * NBLK + blk;
        int st = histD[idx];
        int nx = (idx + 1 < NBKT * NBLK) ? histD[idx + 1] : N_EDGES;
        gbD[b] = st; cntD[b] = nx - st;
        int st2 = histS[idx];
        int nx2 = (idx + 1 < NBKT * NBLK) ? histS[idx + 1] : N_EDGES;
        gbS[b] = st2; cntS[b] = nx2 - st2;
    }
    __syncthreads();
    if (t < 64) {
        int lane = t;
        int base7 = lane * 7;
        int loc[7]; int s7 = 0;
        #pragma unroll
        for (int k = 0; k < 7; k++) { int b = base7 + k; loc[k] = s7; s7 += (b < NBKT) ? cntD[b] : 0; }
        int x = s7;
        #pragma unroll
        for (int off = 1; off < 64; off <<= 1) { int y = __shfl_up(x, off); if (lane >= off) x += y; }
        int excl = x - s7;
        #pragma unroll
        for (int k = 0; k < 7; k++) { int b = base7 + k; if (b < NBKT) { offD[b] = excl + loc[k]; curD[b] = excl + loc[k]; } }
    } else if (t < 128) {
        int lane = t - 64;
        int base7 = lane * 7;
        int loc[7]; int s7 = 0;
        #pragma unroll
        for (int k = 0; k < 7; k++) { int b = base7 + k; loc[k] = s7; s7 += (b < NBKT) ? cntS[b] : 0; }
        int x = s7;
        #pragma unroll
        for (int off = 1; off < 64; off <<= 1) { int y = __shfl_up(x, off); if (lane >= off) x += y; }
        int excl = x - s7;
        #pragma unroll
        for (int k = 0; k < 7; k++) { int b = base7 + k; if (b < NBKT) { offS[b] = excl + loc[k]; curS[b] = excl + loc[k]; } }
    }
    __syncthreads();
    int base = blk * CHUNK;
    for (int i = t; i < CHUNK; i += 512) {
        int e = base + i;
        if (e < N_EDGES) {
            int s = src[e], d = dst[e];
            int pD = atomicAdd(&curD[d >> KSH], 1);
            stageD[pD] = ((d & (BKT - 1)) << 17) | s;
            int pS = atomicAdd(&curS[s >> KSH], 1);
            stageS[pS] = (unsigned short)(s & (BKT - 1));
        }
    }
    __syncthreads();
    int wv = t >> 6, lane = t & 63;
    for (int b = wv; b < NBKT; b += 8) {
        int c = cntD[b], o = offD[b], g = gbD[b];
        for (int i = lane; i < c; i += 64) bufD[g + i] = stageD[o + i];
        int c2 = cntS[b], o2 = offS[b], g2 = gbS[b];
        for (int i = lane; i < c2; i += 64) bufS[g2 + i] = stageS[o2 + i];
    }
}

// ---------------- fused pass2 (512 thr, privatized count bins) ----------------
__global__ __launch_bounds__(512) void k_pass2both(const int* __restrict__ bufD,
                                               const unsigned short* __restrict__ bufS,
                                               const int* __restrict__ histD,
                                               const int* __restrict__ histS,
                                               const float* __restrict__ feat,
                                               int* __restrict__ rowptr, float* __restrict__ norm_dst,
                                               float* __restrict__ norm_src,
                                               int* __restrict__ col, unsigned* __restrict__ feat8) {
    __shared__ int priv[8 * BKT];
    __shared__ int binc[BKT];
    __shared__ int binoff[BKT];
    __shared__ float snorm[BKT];
    int bb = blockIdx.x, t = threadIdx.x;
    int w = t >> 6;
    if (bb < NBKT) {
        int b = bb;
        int start = histD[b * NBLK];
        int end = (b + 1 < NBKT) ? histD[(b + 1) * NBLK] : N_EDGES;
        for (int i = t; i < 8 * BKT; i += 512) priv[i] = 0;
        __syncthreads();
        for (int i = start + t; i < end; i += 512) atomicAdd(&priv[w * BKT + (bufD[i] >> 17)], 1);
        __syncthreads();
        if (t < BKT) {
            int s = 0;
            #pragma unroll
            for (int k = 0; k < 8; k++) s += priv[k * BKT + t];
            binc[t] = s;
        }
        __syncthreads();
        if (t < 64) {
            int base4 = t * 4;
            int loc[4]; int s4 = 0;
            #pragma unroll
            for (int k = 0; k < 4; k++) { loc[k] = s4; s4 += binc[base4 + k]; }
            int x = s4;
            #pragma unroll
            for (int off = 1; off < 64; off <<= 1) {
                int y = __shfl_up(x, off);
                if (t >= off) x += y;
            }
            int excl = x - s4;
            #pragma unroll
            for (int k = 0; k < 4; k++) binoff[base4 + k] = excl + loc[k];
        }
        __syncthreads();
        int nb = N_NODES - b * BKT; if (nb > BKT) nb = BKT;
        if (t < nb) {
            rowptr[b * BKT + t] = start + binoff[t];
            int c = binc[t]; if (c < 1) c = 1;
            norm_dst[b * BKT + t] = rsqrtf((float)c);
        }
        if (b == NBKT - 1 && t == 0) rowptr[N_NODES] = N_EDGES;
        __syncthreads();
        if (t < BKT) binc[t] = binoff[t];
        __syncthreads();
        for (int i = start + t; i < end; i += 512) {
            int v = bufD[i];
            int ld = v >> 17, s = v & 0x1FFFF;
            int p = atomicAdd(&binc[ld], 1);
            col[start + p] = s;
        }
    } else {
        int b = bb - NBKT;
        int start = histS[b * NBLK];
        int end = (b + 1 < NBKT) ? histS[(b + 1) * NBLK] : N_EDGES;
        for (int i = t; i < 8 * BKT; i += 512) priv[i] = 0;
        __syncthreads();
        for (int i = start + t; i < end; i += 512) atomicAdd(&priv[w * BKT + bufS[i]], 1);
        __syncthreads();
        int nb = N_NODES - b * BKT; if (nb > BKT) nb = BKT;
        if (t < nb) {
            int c = 0;
            #pragma unroll
            for (int k = 0; k < 8; k++) c += priv[k * BKT + t];
            if (c < 1) c = 1;
            float sc = rsqrtf((float)c);
            norm_src[b * BKT + t] = sc;
            snorm[t] = sc;
        }
        __syncthreads();
        const float4* fin = (const float4*)feat;
        int nq = nb * 32;
        for (int i = t; i < nq; i += 512) {
            int nl = i >> 5, q = i & 31;
            float sc = snorm[nl];
            float4 v = fin[((size_t)(b * BKT + nl)) * 32 + q];
            unsigned wv = 0;
            wv = __builtin_amdgcn_cvt_pk_fp8_f32(v.x * sc, v.y * sc, wv, 0);
            wv = __builtin_amdgcn_cvt_pk_fp8_f32(v.z * sc, v.w * sc, wv, 1);
            feat8[((size_t)(b * BKT + nl)) * 32 + q] = wv;
        }
    }
}

// ---------------- SpMM (fp8 gather, 8 nodes per wave, 4 edges in flight) ----------------
#define ACC8(r) do {                                                                  \
    auto p0 = __builtin_amdgcn_cvt_pk_f32_fp8((r).x, 0); a0 += p0[0]; a1 += p0[1];    \
    auto p1 = __builtin_amdgcn_cvt_pk_f32_fp8((r).x, 1); a2 += p1[0]; a3 += p1[1];    \
    auto p2 = __builtin_amdgcn_cvt_pk_f32_fp8((r).y, 0); a4 += p2[0]; a5 += p2[1];    \
    auto p3 = __builtin_amdgcn_cvt_pk_f32_fp8((r).y, 1); a6 += p3[0]; a7 += p3[1];    \
    auto p4 = __builtin_amdgcn_cvt_pk_f32_fp8((r).z, 0); a8 += p4[0]; a9 += p4[1];    \
    auto p5 = __builtin_amdgcn_cvt_pk_f32_fp8((r).z, 1); a10 += p5[0]; a11 += p5[1];  \
    auto p6 = __builtin_amdgcn_cvt_pk_f32_fp8((r).w, 0); a12 += p6[0]; a13 += p6[1];  \
    auto p7 = __builtin_amdgcn_cvt_pk_f32_fp8((r).w, 1); a14 += p7[0]; a15 += p7[1];  \
} while (0)

__global__ __launch_bounds__(256) void k_spmm8(const unsigned char* __restrict__ in,
                       const int* __restrict__ rowptr, const int* __restrict__ col,
                       const float* __restrict__ norm_dst, __half2* __restrict__ out) {
    int wid = (blockIdx.x * 256 + threadIdx.x) >> 6;
    int lane = threadIdx.x & 63;
    int rg = lane >> 3, l8 = lane & 7;
    int node = wid * 8 + rg;
    if (node >= N_NODES) return;
    int jb = rowptr[node], je = rowptr[node + 1];
    float a0 = 0.f, a1 = 0.f, a2 = 0.f, a3 = 0.f, a4 = 0.f, a5 = 0.f, a6 = 0.f, a7 = 0.f;
    float a8 = 0.f, a9 = 0.f, a10 = 0.f, a11 = 0.f, a12 = 0.f, a13 = 0.f, a14 = 0.f, a15 = 0.f;
    int j = jb;
    for (; j + 4 <= je; j += 4) {
        int s0 = col[j], s1 = col[j + 1], s2 = col[j + 2], s3 = col[j + 3];
        uint4 r0 = *(const uint4*)&in[(size_t)s0 * 128 + l8 * 16];
        uint4 r1 = *(const uint4*)&in[(size_t)s1 * 128 + l8 * 16];
        uint4 r2 = *(const uint4*)&in[(size_t)s2 * 128 + l8 * 16];
        uint4 r3 = *(const uint4*)&in[(size_t)s3 * 128 + l8 * 16];
        ACC8(r0);
        ACC8(r1);
        ACC8(r2);
        ACC8(r3);
    }
    if (j + 2 <= je) {
        int s0 = col[j], s1 = col[j + 1];
        uint4 r0 = *(const uint4*)&in[(size_t)s0 * 128 + l8 * 16];
        uint4 r1 = *(const uint4*)&in[(size_t)s1 * 128 + l8 * 16];
        ACC8(r0);
        ACC8(r1);
        j += 2;
    }
    if (j < je) {
        int s0 = col[j];
        uint4 r0 = *(const uint4*)&in[(size_t)s0 * 128 + l8 * 16];
        ACC8(r0);
    }
    float nd = norm_dst[node];
    __half2 h0 = __floats2half2_rn(a0 * nd, a1 * nd);
    __half2 h1 = __floats2half2_rn(a2 * nd, a3 * nd);
    __half2 h2 = __floats2half2_rn(a4 * nd, a5 * nd);
    __half2 h3 = __floats2half2_rn(a6 * nd, a7 * nd);
    __half2 h4 = __floats2half2_rn(a8 * nd, a9 * nd);
    __half2 h5 = __floats2half2_rn(a10 * nd, a11 * nd);
    __half2 h6 = __floats2half2_rn(a12 * nd, a13 * nd);
    __half2 h7 = __floats2half2_rn(a14 * nd, a15 * nd);
    uint4 o0, o1;
    o0.x = *(unsigned*)&h0; o0.y = *(unsigned*)&h1;
    o0.z = *(unsigned*)&h2; o0.w = *(unsigned*)&h3;
    o1.x = *(unsigned*)&h4; o1.y = *(unsigned*)&h5;
    o1.z = *(unsigned*)&h6; o1.w = *(unsigned*)&h7;
    *(uint4*)&out[(size_t)node * 64 + l8 * 8] = o0;
    *(uint4*)&out[(size_t)node * 64 + l8 * 8 + 4] = o1;
}

// ---------------- MFMA GEMM: [N,128]f16 @ [128,128] + bias, relu, (opt rowscale) ----------------
template <bool SCALE, bool OUT8>
__global__ __launch_bounds__(256) void k_gemm_mfma(const __half* __restrict__ A,
        const float* __restrict__ W, const float* __restrict__ bias,
        const float* __restrict__ rowscale, void* __restrict__ outp) {
    __shared__ _Float16 lds[128 * 136];
    int tid = threadIdx.x;
    for (int idx = tid * 4; idx < DIM * DIM; idx += 256 * 4) {
        int k = idx >> 7, n = idx & 127;
        float4 w = *(const float4*)&W[idx];
        lds[(n + 0) * 136 + k] = (_Float16)w.x;
        lds[(n + 1) * 136 + k] = (_Float16)w.y;
        lds[(n + 2) * 136 + k] = (_Float16)w.z;
        lds[(n + 3) * 136 + k] = (_Float16)w.w;
    }
    __syncthreads();
    int wv = tid >> 6, lane = tid & 63;
    int rbase = blockIdx.x * 64 + wv * 16;
    int l15 = lane & 15, kg = lane >> 4;
    int arow = rbase + l15; if (arow >= N_NODES) arow = N_NODES - 1;
    const _Float16* Af = (const _Float16*)A + (size_t)arow * DIM + kg * 8;
    f16x8 a0 = *(const f16x8*)(Af + 0);
    f16x8 a1 = *(const f16x8*)(Af + 32);
    f16x8 a2 = *(const f16x8*)(Af + 64);
    f16x8 a3 = *(const f16x8*)(Af + 96);
    f32x4 acc[8];
    #pragma unroll
    for (int nt = 0; nt < 8; nt++) acc[nt] = (f32x4){0.f, 0.f, 0.f, 0.f};
    #pragma unroll
    for (int nt = 0; nt < 8; nt++) {
        const _Float16* bb = &lds[(nt * 16 + l15) * 136 + kg * 8];
        f16x8 b0 = *(const f16x8*)(bb + 0);
        f16x8 b1 = *(const f16x8*)(bb + 32);
        f16x8 b2 = *(const f16x8*)(bb + 64);
        f16x8 b3 = *(const f16x8*)(bb + 96);
        acc[nt] = __builtin_amdgcn_mfma_f32_16x16x32_f16(a0, b0, acc[nt], 0, 0, 0);
        acc[nt] = __builtin_amdgcn_mfma_f32_16x16x32_f16(a1, b1, acc[nt], 0, 0, 0);
        acc[nt] = __builtin_amdgcn_mfma_f32_16x16x32_f16(a2, b2, acc[nt], 0, 0, 0);
        acc[nt] = __builtin_amdgcn_mfma_f32_16x16x32_f16(a3, b3, acc[nt], 0, 0, 0);
    }
    __syncthreads();
    float bsc[4];
    #pragma unroll
    for (int r = 0; r < 4; r++) {
        if (SCALE) {
            int row = rbase + kg * 4 + r; if (row >= N_NODES) row = N_NODES - 1;
            bsc[r] = rowscale[row];
        } else bsc[r] = 1.f;
    }
    #pragma unroll
    for (int nt = 0; nt < 8; nt++) {
        float bv = bias[nt * 16 + l15];
        #pragma unroll
        for (int r = 0; r < 4; r++) {
            float v = fmaxf(acc[nt][r] + bv, 0.f) * bsc[r];
            lds[(size_t)(wv * 16 + kg * 4 + r) * 136 + nt * 16 + l15] = (_Float16)v;
        }
    }
    __syncthreads();
    #pragma unroll
    for (int t = 0; t < 4; t++) {
        int lrow = wv * 16 + t * 4 + kg;
        int grow = rbase + t * 4 + kg;
        f16x8 v = *(const f16x8*)&lds[(size_t)lrow * 136 + l15 * 8];
        if (grow < N_NODES) {
            if (OUT8) {
                unsigned w0 = 0, w1 = 0;
                w0 = __builtin_amdgcn_cvt_pk_fp8_f32((float)v[0], (float)v[1], w0, 0);
                w0 = __builtin_amdgcn_cvt_pk_fp8_f32((float)v[2], (float)v[3], w0, 1);
                w1 = __builtin_amdgcn_cvt_pk_fp8_f32((float)v[4], (float)v[5], w1, 0);
                w1 = __builtin_amdgcn_cvt_pk_fp8_f32((float)v[6], (float)v[7], w1, 1);
                uint2 o; o.x = w0; o.y = w1;
                *(uint2*)&((unsigned char*)outp)[(size_t)grow * 128 + l15 * 8] = o;
            } else {
                *(f16x8*)&((_Float16*)outp)[(size_t)grow * DIM + l15 * 8] = v;
            }
        }
    }
}

// ---------------- per-graph partial feature sums (bounds computed inline) ----------------
__global__ __launch_bounds__(256) void k_graphsum_part(const __half2* __restrict__ h,
                           const int* __restrict__ gids, float* __restrict__ partial) {
    __shared__ float redx[256];
    __shared__ float redy[256];
    __shared__ int sb[2];
    int g = blockIdx.x;
    int c = blockIdx.y;
    if (threadIdx.x == 0) {
        int lo = 0, hi = N_NODES;
        while (lo < hi) { int mid = (lo + hi) >> 1; if (gids[mid] < g) lo = mid + 1; else hi = mid; }
        sb[0] = lo;
        lo = 0; hi = N_NODES;
        while (lo < hi) { int mid = (lo + hi) >> 1; if (gids[mid] <= g) lo = mid + 1; else hi = mid; }
        sb[1] = lo;
    }
    __syncthreads();
    int s = sb[0], e = sb[1];
    int p = threadIdx.x & 63;
    int r = threadIdx.x >> 6;
    int clen = (e - s + GS_CHUNKS - 1) / GS_CHUNKS;
    int b0 = s + c * clen;
    int b1 = b0 + clen; if (b1 > e) b1 = e;
    float ax = 0.f, ay = 0.f;
    for (int nd = b0 + r; nd < b1; nd += 4) {
        float2 f = __half22float2(h[(size_t)nd * 64 + p]);
        ax += f.x; ay += f.y;
    }
    redx[threadIdx.x] = ax; redy[threadIdx.x] = ay;
    __syncthreads();
    if (threadIdx.x < 64) {
        float sx = redx[threadIdx.x] + redx[threadIdx.x + 64] + redx[threadIdx.x + 128] + redx[threadIdx.x + 192];
        float sy = redy[threadIdx.x] + redy[threadIdx.x + 64] + redy[threadIdx.x + 128] + redy[threadIdx.x + 192];
        float* pp = &partial[((size_t)g * GS_CHUNKS + c) * DIM];
        pp[2 * threadIdx.x] = sx;
        pp[2 * threadIdx.x + 1] = sy;
    }
}

// ---------------- fused combine + MLP readout ----------------
__global__ __launch_bounds__(128) void k_mlp(const float* __restrict__ partial,
                      const int* __restrict__ gids,
                      const float* __restrict__ Wm0, const float* __restrict__ bm0,
                      const float* __restrict__ Wm1, const float* __restrict__ bm1,
                      const float* __restrict__ Wm2, const float* __restrict__ bm2,
                      const float* __restrict__ Wm3, const float* __restrict__ bm3,
                      float* __restrict__ out) {
    __shared__ float hb[DIM];
    __shared__ float l0[64];
    __shared__ float l1[32];
    __shared__ float l2[16];
    __shared__ int scnt;
    int g = blockIdx.x;
    int t = threadIdx.x;
    if (t == 0) {
        int lo = 0, hi = N_NODES;
        while (lo < hi) { int mid = (lo + hi) >> 1; if (gids[mid] < g) lo = mid + 1; else hi = mid; }
        int s = lo;
        lo = 0; hi = N_NODES;
        while (lo < hi) { int mid = (lo + hi) >> 1; if (gids[mid] <= g) lo = mid + 1; else hi = mid; }
        int c = lo - s; if (c < 1) c = 1;
        scnt = c;
    }
    __syncthreads();
    float acc = 0.f;
    #pragma unroll
    for (int c = 0; c < GS_CHUNKS; c++)
        acc += partial[((size_t)g * GS_CHUNKS + c) * DIM + t];
    hb[t] = acc / (float)scnt;
    __syncthreads();
    if (t < 64) {
        float a = bm0[t];
        for (int k = 0; k < 128; k++) a += hb[k] * Wm0[k * 64 + t];
        l0[t] = fmaxf(a, 0.f);
    }
    __syncthreads();
    if (t < 32) {
        float a = bm1[t];
        for (int k = 0; k < 64; k++) a += l0[k] * Wm1[k * 32 + t];
        l1[t] = fmaxf(a, 0.f);
    }
    __syncthreads();
    if (t < 16) {
        float a = bm2[t];
        for (int k = 0; k < 32; k++) a += l1[k] * Wm2[k * 16 + t];
        l2[t] = fmaxf(a, 0.f);
    }
    __syncthreads();
    if (t == 0) {
        float a = bm3[0];
        for (int k = 0; k < 16; k++) a += l2[k] * Wm3[k];
        out[g] = a;
    }
}

extern "C" void kernel_launch(void* const* d_in, const int* in_sizes, int n_in,
                              void* d_out, int out_size, void* d_ws, size_t ws_size,
                              hipStream_t stream) {
    const float* feat = (const float*)d_in[0];
    const int*   src  = (const int*)d_in[1];
    const int*   dst  = (const int*)d_in[2];
    const int*   gids = (const int*)d_in[3];
    const float* W1   = (const float*)d_in[5];
    const float* b1   = (const float*)d_in[6];
    const float* W2   = (const float*)d_in[7];
    const float* b2   = (const float*)d_in[8];
    const float* Wm0  = (const float*)d_in[9];
    const float* bm0  = (const float*)d_in[10];
    const float* Wm1  = (const float*)d_in[11];
    const float* bm1  = (const float*)d_in[12];
    const float* Wm2  = (const float*)d_in[13];
    const float* bm2  = (const float*)d_in[14];
    const float* Wm3  = (const float*)d_in[15];
    const float* bm3  = (const float*)d_in[16];
    float* out = (float*)d_out;

    char* ws = (char*)d_ws;
    size_t off = 0;
    auto alloc = [&](size_t bytes) -> void* {
        void* p = ws + off;
        off += (bytes + 511) & ~(size_t)511;
        return p;
    };
    float* norm_src = (float*)alloc((size_t)N_NODES * 4);
    float* norm_dst = (float*)alloc((size_t)N_NODES * 4);
    int* rowptr   = (int*)alloc((size_t)(N_NODES + 1) * 4);
    int* histD    = (int*)alloc((size_t)NBKT * NBLK * 4);
    int* histS    = (int*)alloc((size_t)NBKT * NBLK * 4);
    int* rowtot   = (int*)alloc((size_t)(2 * NBKT) * 4);
    int* bufD     = (int*)alloc((size_t)N_EDGES * 4);
    unsigned short* bufS = (unsigned short*)alloc((size_t)N_EDGES * 2);
    int* col      = (int*)alloc((size_t)N_EDGES * 4);
    unsigned char* feat8 = (unsigned char*)alloc((size_t)N_NODES * DIM);
    unsigned char* h8    = (unsigned char*)alloc((size_t)N_NODES * DIM);
    __half* s16   = (__half*)alloc((size_t)N_NODES * DIM * 2);
    __half* g16   = (__half*)alloc((size_t)N_NODES * DIM * 2);
    float* partial = (float*)alloc((size_t)NG * GS_CHUNKS * DIM * 4);

    hipMemsetAsync(rowtot, 0, (size_t)(2 * NBKT) * 4, stream);

    k_hist1<<<NBLK, 512, 0, stream>>>(src, dst, histD, histS, rowtot);
    k_rowapply<<<2 * NBKT, 512, 0, stream>>>(histD, histS, rowtot);
    k_scatter1<<<NBLK, 512, 0, stream>>>(src, dst, histD, histS, bufD, bufS);
    k_pass2both<<<2 * NBKT, 512, 0, stream>>>(bufD, bufS, histD, histS, feat,
                                              rowptr, norm_dst, norm_src, col, (unsigned*)feat8);

    int sb2 = (N_NODES + 31) / 32;   // 8 nodes per wave, 4 waves per block
    int gb = (N_NODES + 63) / 64;
    k_spmm8<<<sb2, 256, 0, stream>>>(feat8, rowptr, col, norm_dst, (__half2*)s16);
    k_gemm_mfma<true, true><<<gb, 256, 0, stream>>>(s16, W1, b1, norm_src, h8);
    k_spmm8<<<sb2, 256, 0, stream>>>(h8, rowptr, col, norm_dst, (__half2*)s16);
    k_gemm_mfma<false, false><<<gb, 256, 0, stream>>>(s16, W2, b2, nullptr, g16);

    dim3 gsg(NG, GS_CHUNKS);
    k_graphsum_part<<<gsg, 256, 0, stream>>>((const __half2*)g16, gids, partial);
    k_mlp<<<NG, 128, 0, stream>>>(partial, gids, Wm0, bm0, Wm1, bm1, Wm2, bm2, Wm3, bm3, out);
}